// Round 1
// baseline (822.249 us; speedup 1.0000x reference)
//
#include <hip/hip_runtime.h>
#include <hip/hip_fp16.h>
#include <math.h>

// Problem dims (fixed by reference setup_inputs)
#define BB 32
#define TT 2048
#define DD 1024
#define HH 1024
#define MM (BB*TT)   // 65536 rows of the energy GEMM

typedef _Float16 half8 __attribute__((ext_vector_type(8)));
typedef float f32x4 __attribute__((ext_vector_type(4)));

// ---------------------------------------------------------------------------
// prep 1: transpose-cast U (D,H) fp32 row-major -> Ut (H,D) fp16 row-major
// so GEMM B-fragments are contiguous-in-K ds_read_b128, mirroring A.
__global__ void prep_ut_kernel(const float* __restrict__ U,
                               _Float16* __restrict__ Ut) {
    __shared__ float tile[32][33];            // +1 pad: no bank conflicts
    const int bx = blockIdx.x, by = blockIdx.y;
    const int tx = threadIdx.x & 31, ty = threadIdx.x >> 5;  // 32x8 threads
#pragma unroll
    for (int j = 0; j < 4; ++j) {
        const int k = by * 32 + ty + j * 8;   // row of U (k index)
        tile[ty + j * 8][tx] = U[(long)k * HH + bx * 32 + tx];
    }
    __syncthreads();
#pragma unroll
    for (int j = 0; j < 4; ++j) {
        const int n = bx * 32 + ty + j * 8;   // row of Ut (n index)
        Ut[(long)n * DD + by * 32 + tx] = (_Float16)tile[tx][ty + j * 8];
    }
}

// ---------------------------------------------------------------------------
// prep 2: ps[b][n] = sum_d s[b][d] * W[d][n]  (fp32, exact) ; also zero d_out
__global__ void prep_ps_kernel(const float* __restrict__ s,
                               const float* __restrict__ W,
                               float* __restrict__ ps,
                               float* __restrict__ out) {
    const int b = blockIdx.x;                 // 32 blocks
    __shared__ float ss[DD];
    for (int i = threadIdx.x; i < DD; i += 256) ss[i] = s[b * DD + i];
    // zero the output (harness poisons d_out before every launch)
    for (int i = threadIdx.x; i < DD; i += 256) out[b * DD + i] = 0.0f;
    __syncthreads();
    const int n0 = threadIdx.x * 4;           // 256 threads * 4 = 1024 cols
    float ax = 0.f, ay = 0.f, az = 0.f, aw = 0.f;
    for (int d = 0; d < DD; ++d) {
        const float sv = ss[d];               // LDS broadcast
        const float4 w = *(const float4*)(W + (long)d * HH + n0);
        ax += sv * w.x; ay += sv * w.y; az += sv * w.z; aw += sv * w.w;
    }
    float4 r; r.x = ax; r.y = ay; r.z = az; r.w = aw;
    *(float4*)(ps + b * HH + n0) = r;
}

// ---------------------------------------------------------------------------
// Main kernel: energy partials.
// C-tile = h_tile(128xK fp32->fp16) @ Ut_tile^T, epilogue folds
// v[c]*tanhf(C + ps[b][c]) over the tile's 128 columns -> per-row partials.
// epart[slot][row], slot = n_tile*2 + wave_n  (16 slots, deterministic).
// NOTE: mask deliberately NOT applied here — masked rows are overridden to
// -1e9 in the softmax kernel, which makes their score exactly 0.
#define Bb_M 128
#define Bb_N 128
#define Bb_K 32

__global__ __launch_bounds__(256)
void energy_gemm_kernel(const float* __restrict__ h,
                        const _Float16* __restrict__ Ut,
                        const float* __restrict__ ps,
                        const float* __restrict__ v,
                        float* __restrict__ epart) {
    __shared__ _Float16 As[Bb_M][Bb_K];   // 8 KB
    __shared__ _Float16 Bs[Bb_N][Bb_K];   // 8 KB
    __shared__ float ps_s[Bb_N];
    __shared__ float v_s[Bb_N];

    const int nt = blockIdx.x;            // 0..7   (n fastest: L2/L3 reuse of A)
    const int mt = blockIdx.y;            // 0..511
    const int m0 = mt * Bb_M;
    const int n0 = nt * Bb_N;
    const int b  = m0 >> 11;              // 2048 % 128 == 0: one batch per tile
    const int tid  = threadIdx.x;
    const int wave = tid >> 6;
    const int lane = tid & 63;
    const int wm = wave >> 1;             // wave row (0..1) -> 64 rows each
    const int wn = wave & 1;              // wave col (0..1) -> 64 cols each

    if (tid < Bb_N) {
        ps_s[tid] = ps[b * HH + n0 + tid];
        v_s[tid]  = v[n0 + tid];
    }

    // staging maps: thread -> (row, 16-element k-segment)
    const int arow = tid >> 1;
    const int aseg = (tid & 1) * 16;
    const float*    ap = h  + (long)(m0 + arow) * DD + aseg;
    const _Float16* bp = Ut + (long)(n0 + arow) * DD + aseg;

    f32x4 acc[4][4];
#pragma unroll
    for (int i = 0; i < 4; ++i)
#pragma unroll
        for (int j = 0; j < 4; ++j) acc[i][j] = (f32x4)0.0f;

    const int lk = (lane >> 4) * 8;       // k-offset of this lane's fragment
    const int lr = lane & 15;             // row/col within 16x16 tile

#pragma unroll 1
    for (int k0 = 0; k0 < DD; k0 += Bb_K) {
        // global loads first (in flight across the barrier)
        const float4 f0 = *(const float4*)(ap + k0);
        const float4 f1 = *(const float4*)(ap + k0 + 4);
        const float4 f2 = *(const float4*)(ap + k0 + 8);
        const float4 f3 = *(const float4*)(ap + k0 + 12);
        const half8 bv0 = *(const half8*)(bp + k0);
        const half8 bv1 = *(const half8*)(bp + k0 + 8);

        __syncthreads();  // previous iter's fragment reads complete

        half8 h0, h1;
        h0[0] = (_Float16)f0.x; h0[1] = (_Float16)f0.y;
        h0[2] = (_Float16)f0.z; h0[3] = (_Float16)f0.w;
        h0[4] = (_Float16)f1.x; h0[5] = (_Float16)f1.y;
        h0[6] = (_Float16)f1.z; h0[7] = (_Float16)f1.w;
        h1[0] = (_Float16)f2.x; h1[1] = (_Float16)f2.y;
        h1[2] = (_Float16)f2.z; h1[3] = (_Float16)f2.w;
        h1[4] = (_Float16)f3.x; h1[5] = (_Float16)f3.y;
        h1[6] = (_Float16)f3.z; h1[7] = (_Float16)f3.w;
        *(half8*)&As[arow][aseg]     = h0;
        *(half8*)&As[arow][aseg + 8] = h1;
        *(half8*)&Bs[arow][aseg]     = bv0;
        *(half8*)&Bs[arow][aseg + 8] = bv1;

        __syncthreads();

        half8 af[4], bf[4];
#pragma unroll
        for (int tm = 0; tm < 4; ++tm)
            af[tm] = *(const half8*)&As[wm * 64 + tm * 16 + lr][lk];
#pragma unroll
        for (int tn = 0; tn < 4; ++tn)
            bf[tn] = *(const half8*)&Bs[wn * 64 + tn * 16 + lr][lk];
#pragma unroll
        for (int tm = 0; tm < 4; ++tm)
#pragma unroll
            for (int tn = 0; tn < 4; ++tn)
                acc[tm][tn] = __builtin_amdgcn_mfma_f32_16x16x32_f16(
                    af[tm], bf[tn], acc[tm][tn], 0, 0, 0);
    }

    // Epilogue: per-row partial energy over this wave's 64 columns.
    // C/D layout: col = lane&15, row = (lane>>4)*4 + reg   [guide §3]
    float part[4][4];
#pragma unroll
    for (int tm = 0; tm < 4; ++tm) {
#pragma unroll
        for (int r = 0; r < 4; ++r) {
            float p = 0.f;
#pragma unroll
            for (int tn = 0; tn < 4; ++tn) {
                const int cl = wn * 64 + tn * 16 + lr;  // local col in [0,128)
                p += v_s[cl] * tanhf(acc[tm][tn][r] + ps_s[cl]);
            }
            part[tm][r] = p;
        }
    }
    // reduce across the 16 lanes holding different cols of the same rows
#pragma unroll
    for (int off = 1; off < 16; off <<= 1)
#pragma unroll
        for (int tm = 0; tm < 4; ++tm)
#pragma unroll
            for (int r = 0; r < 4; ++r)
                part[tm][r] += __shfl_xor(part[tm][r], off, 64);

    if ((lane & 15) == 0) {
        const int slot = nt * 2 + wn;      // 16 deterministic partial slots
#pragma unroll
        for (int tm = 0; tm < 4; ++tm)
#pragma unroll
            for (int r = 0; r < 4; ++r) {
                const int row = m0 + wm * 64 + tm * 16 + (lane >> 4) * 4 + r;
                epart[(long)slot * MM + row] = part[tm][r];
            }
    }
}

// ---------------------------------------------------------------------------
// softmax over T per batch; masked rows forced to -1e9 (=> score exactly 0)
__global__ void softmax_kernel(const float* __restrict__ epart,
                               const int* __restrict__ mask,
                               float* __restrict__ score) {
    const int b = blockIdx.x;             // 32 blocks
    const int tid = threadIdx.x;          // 256
    float e[8];
    float mx = -1e30f;
#pragma unroll
    for (int i = 0; i < 8; ++i) {
        const int t = i * 256 + tid;
        const long row = (long)b * TT + t;
        float sum = 0.f;
#pragma unroll
        for (int p = 0; p < 16; ++p) sum += epart[(long)p * MM + row];
        if (mask[row] == 0) sum = -1e9f;
        e[i] = sum;
        mx = fmaxf(mx, sum);
    }
#pragma unroll
    for (int off = 32; off > 0; off >>= 1) mx = fmaxf(mx, __shfl_xor(mx, off, 64));
    __shared__ float r4[4];
    if ((tid & 63) == 0) r4[tid >> 6] = mx;
    __syncthreads();
    mx = fmaxf(fmaxf(r4[0], r4[1]), fmaxf(r4[2], r4[3]));

    float tot = 0.f;
#pragma unroll
    for (int i = 0; i < 8; ++i) { e[i] = expf(e[i] - mx); tot += e[i]; }
#pragma unroll
    for (int off = 32; off > 0; off >>= 1) tot += __shfl_xor(tot, off, 64);
    __shared__ float s4[4];
    __syncthreads();
    if ((tid & 63) == 0) s4[tid >> 6] = tot;
    __syncthreads();
    tot = s4[0] + s4[1] + s4[2] + s4[3];
    const float inv = 1.0f / tot;
#pragma unroll
    for (int i = 0; i < 8; ++i)
        score[(long)b * TT + i * 256 + tid] = e[i] * inv;
}

// ---------------------------------------------------------------------------
// context[b][d] = sum_t score[b][t] * h[b][t][d]; skip score==0 rows (masked)
__global__ void context_kernel(const float* __restrict__ h,
                               const float* __restrict__ score,
                               float* __restrict__ out) {
    const int tc = blockIdx.x;            // 16 t-chunks of 128
    const int b  = blockIdx.y;            // 32 batches
    const int d0 = threadIdx.x * 4;       // 256 threads * 4 = 1024
    float ax = 0.f, ay = 0.f, az = 0.f, aw = 0.f;
    for (int i = 0; i < 128; ++i) {
        const int t = tc * 128 + i;
        const float sc = score[(long)b * TT + t];
        if (sc != 0.0f) {                 // block-uniform branch
            const float4 hv = *(const float4*)(h + ((long)(b * TT + t)) * DD + d0);
            ax += sc * hv.x; ay += sc * hv.y; az += sc * hv.z; aw += sc * hv.w;
        }
    }
    atomicAdd(&out[b * DD + d0 + 0], ax);
    atomicAdd(&out[b * DD + d0 + 1], ay);
    atomicAdd(&out[b * DD + d0 + 2], az);
    atomicAdd(&out[b * DD + d0 + 3], aw);
}

// ---------------------------------------------------------------------------
extern "C" void kernel_launch(void* const* d_in, const int* in_sizes, int n_in,
                              void* d_out, int out_size, void* d_ws, size_t ws_size,
                              hipStream_t stream) {
    const float* s    = (const float*)d_in[0];  // (1,B,D)
    const float* h    = (const float*)d_in[1];  // (B,T,D)
    const int*   mask = (const int*)  d_in[2];  // (B,T)
    const float* W    = (const float*)d_in[3];  // (D,H)
    const float* U    = (const float*)d_in[4];  // (D,H)
    const float* v    = (const float*)d_in[5];  // (H,1)
    float* out = (float*)d_out;                 // (B,D)

    // workspace layout (~6.6 MB total)
    char* ws = (char*)d_ws;
    _Float16* Ut   = (_Float16*)ws;                                  // 2 MB
    float*    ps   = (float*)(ws + (2u << 20));                      // 128 KB
    float*    ep   = (float*)(ws + (2u << 20) + (128u << 10));       // 4 MB
    float*    scr  = (float*)(ws + (2u << 20) + (128u << 10) + (4u << 20)); // 256 KB

    prep_ut_kernel  <<<dim3(32, 32), 256, 0, stream>>>(U, Ut);
    prep_ps_kernel  <<<32,           256, 0, stream>>>(s, W, ps, out);
    energy_gemm_kernel<<<dim3(8, 512), 256, 0, stream>>>(h, Ut, ps, v, ep);
    softmax_kernel  <<<32,           256, 0, stream>>>(ep, mask, scr);
    context_kernel  <<<dim3(16, 32), 256, 0, stream>>>(h, scr, out);
}

// Round 2
// 683.058 us; speedup vs baseline: 1.2038x; 1.2038x over previous
//
#include <hip/hip_runtime.h>
#include <hip/hip_fp16.h>
#include <math.h>

// Problem dims (fixed by reference setup_inputs)
#define BB 32
#define TT 2048
#define DD 1024
#define HH 1024
#define MM (BB*TT)   // 65536 rows of the energy GEMM

typedef _Float16 half8 __attribute__((ext_vector_type(8)));
typedef float f32x4 __attribute__((ext_vector_type(4)));

// fast tanh: (e^2x - 1)/(e^2x + 1), clamped so e^2x never overflows.
// rel err ~1e-5, negligible vs fp16-GEMM error (~2e-3 absmax, thr 9.7e-3).
__device__ __forceinline__ float tanh_fast(float x) {
    float cx = fminf(fmaxf(x, -10.0f), 10.0f);
    float e2 = __expf(2.0f * cx);
    return (e2 - 1.0f) / (e2 + 1.0f);
}

// ---------------------------------------------------------------------------
// cast h (B,T,D) fp32 -> fp16, contiguous. 32768 blocks x 256 thr x 8 elems.
__global__ void cast_h_kernel(const float* __restrict__ h,
                              _Float16* __restrict__ h16) {
    const long i0 = ((long)blockIdx.x * 256 + threadIdx.x) * 8;
    const float4 f0 = *(const float4*)(h + i0);
    const float4 f1 = *(const float4*)(h + i0 + 4);
    half8 o;
    o[0] = (_Float16)f0.x; o[1] = (_Float16)f0.y;
    o[2] = (_Float16)f0.z; o[3] = (_Float16)f0.w;
    o[4] = (_Float16)f1.x; o[5] = (_Float16)f1.y;
    o[6] = (_Float16)f1.z; o[7] = (_Float16)f1.w;
    *(half8*)(h16 + i0) = o;
}

// ---------------------------------------------------------------------------
// prep 1: transpose-cast U (D,H) fp32 row-major -> Ut (H,D) fp16 row-major
__global__ void prep_ut_kernel(const float* __restrict__ U,
                               _Float16* __restrict__ Ut) {
    __shared__ float tile[32][33];            // +1 pad: no bank conflicts
    const int bx = blockIdx.x, by = blockIdx.y;
    const int tx = threadIdx.x & 31, ty = threadIdx.x >> 5;  // 32x8 threads
#pragma unroll
    for (int j = 0; j < 4; ++j) {
        const int k = by * 32 + ty + j * 8;   // row of U (k index)
        tile[ty + j * 8][tx] = U[(long)k * HH + bx * 32 + tx];
    }
    __syncthreads();
#pragma unroll
    for (int j = 0; j < 4; ++j) {
        const int n = bx * 32 + ty + j * 8;   // row of Ut (n index)
        Ut[(long)n * DD + by * 32 + tx] = (_Float16)tile[tx][ty + j * 8];
    }
}

// ---------------------------------------------------------------------------
// prep 2: ps[b][n] = sum_d s[b][d] * W[d][n]  (fp32) ; also zero d_out.
// grid (4 nseg, 32 b) x 256 threads: coalesced 1KB row segments of W,
// shared across the 32 b-blocks via L2.
__global__ void prep_ps_kernel(const float* __restrict__ s,
                               const float* __restrict__ W,
                               float* __restrict__ ps,
                               float* __restrict__ out) {
    const int nseg = blockIdx.x, b = blockIdx.y;
    const int n = nseg * 256 + threadIdx.x;
    __shared__ float ss[DD];
#pragma unroll
    for (int j = 0; j < 4; ++j)
        ss[threadIdx.x + j * 256] = s[b * DD + threadIdx.x + j * 256];
    out[b * HH + n] = 0.0f;                   // harness poisons d_out
    __syncthreads();
    float a0 = 0.f, a1 = 0.f, a2 = 0.f, a3 = 0.f;
#pragma unroll 4
    for (int d = 0; d < DD; d += 4) {
        a0 += ss[d + 0] * W[(long)(d + 0) * HH + n];
        a1 += ss[d + 1] * W[(long)(d + 1) * HH + n];
        a2 += ss[d + 2] * W[(long)(d + 2) * HH + n];
        a3 += ss[d + 3] * W[(long)(d + 3) * HH + n];
    }
    ps[b * HH + n] = (a0 + a1) + (a2 + a3);
}

// ---------------------------------------------------------------------------
// Main kernel: energy partials (templated on whether A comes pre-cast fp16).
#define Bb_M 128
#define Bb_N 128
#define Bb_K 32
#define AP   40   // padded LDS row length in halves: group=(5*row+chunk)%8 -> conflict-free

template <bool A16>
__global__ __launch_bounds__(256)
void energy_gemm_kernel(const float* __restrict__ h32,
                        const _Float16* __restrict__ h16,
                        const _Float16* __restrict__ Ut,
                        const float* __restrict__ ps,
                        const float* __restrict__ v,
                        float* __restrict__ epart) {
    __shared__ _Float16 As[Bb_M][AP];   // 10 KB
    __shared__ _Float16 Bs[Bb_N][AP];   // 10 KB
    __shared__ float ps_s[Bb_N];
    __shared__ float v_s[Bb_N];

    const int nt = blockIdx.x;            // 0..7   (n fastest: L2/L3 reuse of A)
    const int mt = blockIdx.y;            // 0..511
    const int m0 = mt * Bb_M;
    const int n0 = nt * Bb_N;
    const int b  = m0 >> 11;              // 2048 % 128 == 0: one batch per tile
    const int tid  = threadIdx.x;
    const int wave = tid >> 6;
    const int lane = tid & 63;
    const int wm = wave >> 1;             // wave row (0..1) -> 64 rows each
    const int wn = wave & 1;              // wave col (0..1) -> 64 cols each

    if (tid < Bb_N) {
        ps_s[tid] = ps[b * HH + n0 + tid];
        v_s[tid]  = v[n0 + tid];
    }

    // staging maps: thread -> (row, 16-element k-segment)
    const int arow = tid >> 1;
    const int aseg = (tid & 1) * 16;
    const float*    ap32 = h32 + (long)(m0 + arow) * DD + aseg;
    const _Float16* ap16 = h16 + (long)(m0 + arow) * DD + aseg;
    const _Float16* bp   = Ut  + (long)(n0 + arow) * DD + aseg;

    f32x4 acc[4][4];
#pragma unroll
    for (int i = 0; i < 4; ++i)
#pragma unroll
        for (int j = 0; j < 4; ++j) acc[i][j] = (f32x4)0.0f;

    const int lk = (lane >> 4) * 8;       // k-offset of this lane's fragment
    const int lr = lane & 15;             // row/col within 16x16 tile

#pragma unroll 1
    for (int k0 = 0; k0 < DD; k0 += Bb_K) {
        // global loads first (in flight across the barrier)
        half8 a0, a1;
        if (A16) {
            a0 = *(const half8*)(ap16 + k0);
            a1 = *(const half8*)(ap16 + k0 + 8);
        } else {
            const float4 f0 = *(const float4*)(ap32 + k0);
            const float4 f1 = *(const float4*)(ap32 + k0 + 4);
            const float4 f2 = *(const float4*)(ap32 + k0 + 8);
            const float4 f3 = *(const float4*)(ap32 + k0 + 12);
            a0[0] = (_Float16)f0.x; a0[1] = (_Float16)f0.y;
            a0[2] = (_Float16)f0.z; a0[3] = (_Float16)f0.w;
            a0[4] = (_Float16)f1.x; a0[5] = (_Float16)f1.y;
            a0[6] = (_Float16)f1.z; a0[7] = (_Float16)f1.w;
            a1[0] = (_Float16)f2.x; a1[1] = (_Float16)f2.y;
            a1[2] = (_Float16)f2.z; a1[3] = (_Float16)f2.w;
            a1[4] = (_Float16)f3.x; a1[5] = (_Float16)f3.y;
            a1[6] = (_Float16)f3.z; a1[7] = (_Float16)f3.w;
        }
        const half8 bv0 = *(const half8*)(bp + k0);
        const half8 bv1 = *(const half8*)(bp + k0 + 8);

        __syncthreads();  // previous iter's fragment reads complete

        *(half8*)&As[arow][aseg]     = a0;
        *(half8*)&As[arow][aseg + 8] = a1;
        *(half8*)&Bs[arow][aseg]     = bv0;
        *(half8*)&Bs[arow][aseg + 8] = bv1;

        __syncthreads();

        half8 af[4], bf[4];
#pragma unroll
        for (int tm = 0; tm < 4; ++tm)
            af[tm] = *(const half8*)&As[wm * 64 + tm * 16 + lr][lk];
#pragma unroll
        for (int tn = 0; tn < 4; ++tn)
            bf[tn] = *(const half8*)&Bs[wn * 64 + tn * 16 + lr][lk];
#pragma unroll
        for (int tm = 0; tm < 4; ++tm)
#pragma unroll
            for (int tn = 0; tn < 4; ++tn)
                acc[tm][tn] = __builtin_amdgcn_mfma_f32_16x16x32_f16(
                    af[tm], bf[tn], acc[tm][tn], 0, 0, 0);
    }

    // Epilogue: per-row partial energy over this wave's 64 columns.
    // C/D layout: col = lane&15, row = (lane>>4)*4 + reg
    float part[4][4];
#pragma unroll
    for (int tm = 0; tm < 4; ++tm) {
#pragma unroll
        for (int r = 0; r < 4; ++r) {
            float p = 0.f;
#pragma unroll
            for (int tn = 0; tn < 4; ++tn) {
                const int cl = wn * 64 + tn * 16 + lr;  // local col in [0,128)
                p += v_s[cl] * tanh_fast(acc[tm][tn][r] + ps_s[cl]);
            }
            part[tm][r] = p;
        }
    }
#pragma unroll
    for (int off = 1; off < 16; off <<= 1)
#pragma unroll
        for (int tm = 0; tm < 4; ++tm)
#pragma unroll
            for (int r = 0; r < 4; ++r)
                part[tm][r] += __shfl_xor(part[tm][r], off, 64);

    if ((lane & 15) == 0) {
        const int slot = nt * 2 + wn;      // 16 deterministic partial slots
#pragma unroll
        for (int tm = 0; tm < 4; ++tm)
#pragma unroll
            for (int r = 0; r < 4; ++r) {
                const int row = m0 + wm * 64 + tm * 16 + (lane >> 4) * 4 + r;
                epart[(long)slot * MM + row] = part[tm][r];
            }
    }
}

// ---------------------------------------------------------------------------
// softmax over T per batch; masked rows forced to -1e9 (=> score exactly 0)
__global__ void softmax_kernel(const float* __restrict__ epart,
                               const int* __restrict__ mask,
                               float* __restrict__ score) {
    const int b = blockIdx.x;             // 32 blocks
    const int tid = threadIdx.x;          // 256
    float e[8];
    float mx = -1e30f;
#pragma unroll
    for (int i = 0; i < 8; ++i) {
        const int t = i * 256 + tid;
        const long row = (long)b * TT + t;
        float sum = 0.f;
#pragma unroll
        for (int p = 0; p < 16; ++p) sum += epart[(long)p * MM + row];
        if (mask[row] == 0) sum = -1e9f;
        e[i] = sum;
        mx = fmaxf(mx, sum);
    }
#pragma unroll
    for (int off = 32; off > 0; off >>= 1) mx = fmaxf(mx, __shfl_xor(mx, off, 64));
    __shared__ float r4[4];
    if ((tid & 63) == 0) r4[tid >> 6] = mx;
    __syncthreads();
    mx = fmaxf(fmaxf(r4[0], r4[1]), fmaxf(r4[2], r4[3]));

    float tot = 0.f;
#pragma unroll
    for (int i = 0; i < 8; ++i) { e[i] = expf(e[i] - mx); tot += e[i]; }
#pragma unroll
    for (int off = 32; off > 0; off >>= 1) tot += __shfl_xor(tot, off, 64);
    __shared__ float s4[4];
    __syncthreads();
    if ((tid & 63) == 0) s4[tid >> 6] = tot;
    __syncthreads();
    tot = s4[0] + s4[1] + s4[2] + s4[3];
    const float inv = 1.0f / tot;
#pragma unroll
    for (int i = 0; i < 8; ++i)
        score[(long)b * TT + i * 256 + tid] = e[i] * inv;
}

// ---------------------------------------------------------------------------
// context[b][d] = sum_t score[b][t] * h[b][t][d]; skip score==0 rows (masked)
template <bool A16>
__global__ void context_kernel(const float* __restrict__ h32,
                               const _Float16* __restrict__ h16,
                               const float* __restrict__ score,
                               float* __restrict__ out) {
    const int tc = blockIdx.x;            // 16 t-chunks of 128
    const int b  = blockIdx.y;            // 32 batches
    const int d0 = threadIdx.x * 8;       // 128 threads * 8 = 1024
    float a[8];
#pragma unroll
    for (int j = 0; j < 8; ++j) a[j] = 0.f;
    for (int i = 0; i < 128; ++i) {
        const int t = tc * 128 + i;
        const float sc = score[(long)b * TT + t];
        if (sc != 0.0f) {                 // block-uniform branch
            if (A16) {
                const half8 hv = *(const half8*)(h16 + ((long)(b * TT + t)) * DD + d0);
#pragma unroll
                for (int j = 0; j < 8; ++j) a[j] += sc * (float)hv[j];
            } else {
                const float4 h0 = *(const float4*)(h32 + ((long)(b * TT + t)) * DD + d0);
                const float4 h1 = *(const float4*)(h32 + ((long)(b * TT + t)) * DD + d0 + 4);
                a[0] += sc * h0.x; a[1] += sc * h0.y; a[2] += sc * h0.z; a[3] += sc * h0.w;
                a[4] += sc * h1.x; a[5] += sc * h1.y; a[6] += sc * h1.z; a[7] += sc * h1.w;
            }
        }
    }
#pragma unroll
    for (int j = 0; j < 8; ++j) atomicAdd(&out[b * DD + d0 + j], a[j]);
}

// ---------------------------------------------------------------------------
extern "C" void kernel_launch(void* const* d_in, const int* in_sizes, int n_in,
                              void* d_out, int out_size, void* d_ws, size_t ws_size,
                              hipStream_t stream) {
    const float* s    = (const float*)d_in[0];  // (1,B,D)
    const float* h    = (const float*)d_in[1];  // (B,T,D)
    const int*   mask = (const int*)  d_in[2];  // (B,T)
    const float* W    = (const float*)d_in[3];  // (D,H)
    const float* U    = (const float*)d_in[4];  // (D,H)
    const float* v    = (const float*)d_in[5];  // (H,1)
    float* out = (float*)d_out;                 // (B,D)

    // workspace layout
    const size_t sz_h16 = (size_t)BB * TT * DD * sizeof(_Float16); // 134 MB
    const size_t sz_ut  = (size_t)HH * DD * sizeof(_Float16);      // 2 MB
    const size_t sz_ps  = (size_t)BB * HH * sizeof(float);         // 128 KB
    const size_t sz_ep  = (size_t)16 * MM * sizeof(float);         // 4 MB
    const size_t sz_sc  = (size_t)BB * TT * sizeof(float);         // 256 KB
    const bool use16 = ws_size >= sz_h16 + sz_ut + sz_ps + sz_ep + sz_sc;

    char* ws = (char*)d_ws;
    _Float16* h16 = (_Float16*)ws;
    size_t off = use16 ? sz_h16 : 0;
    _Float16* Ut  = (_Float16*)(ws + off); off += sz_ut;
    float*    ps  = (float*)(ws + off);    off += sz_ps;
    float*    ep  = (float*)(ws + off);    off += sz_ep;
    float*    scr = (float*)(ws + off);

    if (use16)
        cast_h_kernel<<<32768, 256, 0, stream>>>(h, h16);
    prep_ut_kernel<<<dim3(32, 32), 256, 0, stream>>>(U, Ut);
    prep_ps_kernel<<<dim3(4, 32), 256, 0, stream>>>(s, W, ps, out);
    if (use16) {
        energy_gemm_kernel<true><<<dim3(8, 512), 256, 0, stream>>>(h, h16, Ut, ps, v, ep);
        softmax_kernel<<<32, 256, 0, stream>>>(ep, mask, scr);
        context_kernel<true><<<dim3(16, 32), 128, 0, stream>>>(h, h16, scr, out);
    } else {
        energy_gemm_kernel<false><<<dim3(8, 512), 256, 0, stream>>>(h, h16, Ut, ps, v, ep);
        softmax_kernel<<<32, 256, 0, stream>>>(ep, mask, scr);
        context_kernel<false><<<dim3(16, 32), 128, 0, stream>>>(h, h16, scr, out);
    }
}

// Round 3
// 561.214 us; speedup vs baseline: 1.4651x; 1.2171x over previous
//
#include <hip/hip_runtime.h>
#include <hip/hip_fp16.h>
#include <math.h>

// Problem dims (fixed by reference setup_inputs)
#define BB 32
#define TT 2048
#define DD 1024
#define HH 1024
#define MM (BB*TT)

typedef _Float16 half8 __attribute__((ext_vector_type(8)));
typedef float f32x4 __attribute__((ext_vector_type(4)));

__device__ __forceinline__ float tanh_fast(float x) {
    float cx = fminf(fmaxf(x, -10.0f), 10.0f);
    float e2 = __expf(2.0f * cx);
    return (e2 - 1.0f) / (e2 + 1.0f);
}

// async global->LDS DMA, 16 B per lane. LDS dest = wave-uniform base + lane*16.
__device__ __forceinline__ void load_lds16(const _Float16* g, _Float16* l) {
    __builtin_amdgcn_global_load_lds(
        (const __attribute__((address_space(1))) void*)g,
        (__attribute__((address_space(3))) void*)l, 16, 0, 0);
}

// ---------------------------------------------------------------------------
// compact: per batch, list of unmasked t's (sorted), count, pad to x128.
__global__ void compact_kernel(const int* __restrict__ mask,
                               int* __restrict__ rowlist,
                               int* __restrict__ cnts) {
    const int b = blockIdx.x, tid = threadIdx.x;       // 32 blocks x 256
    const int lane = tid & 63, w = tid >> 6;
    const int* mb = mask + b * TT;
    const int t0 = tid * 8;
    int m[8], c = 0;
#pragma unroll
    for (int j = 0; j < 8; ++j) { m[j] = (mb[t0 + j] != 0); c += m[j]; }
    int pref = c;                                      // wave inclusive scan
#pragma unroll
    for (int off = 1; off < 64; off <<= 1) {
        int nv = __shfl_up(pref, off, 64);
        if (lane >= off) pref += nv;
    }
    __shared__ int wsum[4];
    if (lane == 63) wsum[w] = pref;
    __syncthreads();
    int wbase = 0;
    for (int i = 0; i < w; ++i) wbase += wsum[i];
    int pos = wbase + pref - c;                        // exclusive prefix
#pragma unroll
    for (int j = 0; j < 8; ++j)
        if (m[j]) rowlist[b * TT + pos++] = t0 + j;
    const int total = wsum[0] + wsum[1] + wsum[2] + wsum[3];
    if (tid == 0) cnts[b] = total;
    __syncthreads();                                   // rowlist writes visible
    const int padded = ((total + 127) >> 7) << 7;
    const int lastt = (total > 0) ? rowlist[b * TT + total - 1] : 0;
    for (int ci = total + tid; ci < padded; ci += 256)
        rowlist[b * TT + ci] = lastt;                  // duplicate last row
}

// tile table: global m-tile -> (batch, ci base)
__global__ void tiles_kernel(const int* __restrict__ cnts,
                             int* __restrict__ tile_b,
                             int* __restrict__ tile_ci,
                             int* __restrict__ ntiles) {
    if (threadIdx.x == 0) {
        int tot = 0;
        for (int b = 0; b < BB; ++b) {
            const int nt = (cnts[b] + 127) >> 7;
            for (int i = 0; i < nt; ++i) { tile_b[tot] = b; tile_ci[tot] = i * 128; ++tot; }
        }
        *ntiles = tot;
    }
}

// ---------------------------------------------------------------------------
// cast h fp32->fp16, unmasked rows only (masked never read downstream).
__global__ void cast_h_kernel(const float* __restrict__ h,
                              const int* __restrict__ mask,
                              _Float16* __restrict__ h16) {
    const int row = blockIdx.x * 2 + (threadIdx.x >> 7);   // 2 rows/block
    if (mask[row] == 0) return;                            // wave-uniform
    const int c = (threadIdx.x & 127) * 8;
    const long base = (long)row * DD + c;
    const float4 f0 = *(const float4*)(h + base);
    const float4 f1 = *(const float4*)(h + base + 4);
    half8 o;
    o[0] = (_Float16)f0.x; o[1] = (_Float16)f0.y;
    o[2] = (_Float16)f0.z; o[3] = (_Float16)f0.w;
    o[4] = (_Float16)f1.x; o[5] = (_Float16)f1.y;
    o[6] = (_Float16)f1.z; o[7] = (_Float16)f1.w;
    *(half8*)(h16 + base) = o;
}

// ---------------------------------------------------------------------------
// transpose-cast U (D,H) -> Ut (H,D) fp16
__global__ void prep_ut_kernel(const float* __restrict__ U,
                               _Float16* __restrict__ Ut) {
    __shared__ float tile[32][33];
    const int bx = blockIdx.x, by = blockIdx.y;
    const int tx = threadIdx.x & 31, ty = threadIdx.x >> 5;
#pragma unroll
    for (int j = 0; j < 4; ++j)
        tile[ty + j * 8][tx] = U[(long)(by * 32 + ty + j * 8) * HH + bx * 32 + tx];
    __syncthreads();
#pragma unroll
    for (int j = 0; j < 4; ++j)
        Ut[(long)(bx * 32 + ty + j * 8) * DD + by * 32 + tx] =
            (_Float16)tile[tx][ty + j * 8];
}

// ---------------------------------------------------------------------------
// ps[b][n] = s[b]·W[:,n] ; zero d_out.  grid (32 b, 4 nseg): b-fastest so the
// 32 b-blocks of one nseg share W segments in L2. 8-deep ILP hides latency.
__global__ void prep_ps_kernel(const float* __restrict__ s,
                               const float* __restrict__ W,
                               float* __restrict__ ps,
                               float* __restrict__ out) {
    const int b = blockIdx.x, nseg = blockIdx.y;
    const int n = nseg * 256 + threadIdx.x;
    __shared__ float ss[DD];
#pragma unroll
    for (int j = 0; j < 4; ++j)
        ss[threadIdx.x + j * 256] = s[b * DD + threadIdx.x + j * 256];
    out[b * DD + n] = 0.0f;                    // harness poisons d_out
    __syncthreads();
    float a[8];
#pragma unroll
    for (int j = 0; j < 8; ++j) a[j] = 0.f;
    for (int d = 0; d < DD; d += 8) {
#pragma unroll
        for (int j = 0; j < 8; ++j)
            a[j] += ss[d + j] * W[(long)(d + j) * HH + n];
    }
    ps[b * HH + n] = ((a[0]+a[1])+(a[2]+a[3])) + ((a[4]+a[5])+(a[6]+a[7]));
}

// ---------------------------------------------------------------------------
// energy GEMM on compacted rows, global_load_lds staging (gathered A rows).
#define Bb_K 32

__global__ __launch_bounds__(256)
void energy_gemm_kernel(const _Float16* __restrict__ h16,
                        const _Float16* __restrict__ Ut,
                        const float* __restrict__ ps,
                        const float* __restrict__ v,
                        const int* __restrict__ rowlist,
                        const int* __restrict__ tile_b,
                        const int* __restrict__ tile_ci,
                        const int* __restrict__ ntiles,
                        float* __restrict__ epart) {
    const int mt = blockIdx.y;
    if (mt >= *ntiles) return;                 // uniform, before any barrier
    __shared__ _Float16 As[128][32];           // 8 KB, unpadded (DMA layout)
    __shared__ _Float16 Bs[128][32];           // 8 KB
    __shared__ float ps_s[128];
    __shared__ float v_s[128];
    __shared__ int   rl[128];

    const int nt = blockIdx.x;
    const int b   = tile_b[mt];
    const int ci0 = tile_ci[mt];
    const int n0  = nt * 128;
    const int tid = threadIdx.x;
    const int wave = tid >> 6, lane = tid & 63;
    const int wm = wave >> 1, wn = wave & 1;

    if (tid < 128) {
        ps_s[tid] = ps[b * HH + n0 + tid];
        v_s[tid]  = v[n0 + tid];
        rl[tid]   = rowlist[b * TT + ci0 + tid];
    }
    __syncthreads();

    // staging map: lane i of wave w -> LDS row w*32 + (i>>2), 16B seg (i&3)
    const int srow = wave * 32 + (lane >> 2);
    const int sseg = (lane & 3) * 8;           // halves
    const _Float16* gA0 = h16 + ((long)b * TT + rl[srow])      * DD + sseg;
    const _Float16* gA1 = h16 + ((long)b * TT + rl[srow + 16]) * DD + sseg;
    const _Float16* gB0 = Ut + (long)(n0 + srow) * DD + sseg;
    const _Float16* gB1 = gB0 + 16 * DD;
    _Float16* lA0 = &As[wave * 32][0];
    _Float16* lA1 = &As[wave * 32 + 16][0];
    _Float16* lB0 = &Bs[wave * 32][0];
    _Float16* lB1 = &Bs[wave * 32 + 16][0];

    f32x4 acc[4][4];
#pragma unroll
    for (int i = 0; i < 4; ++i)
#pragma unroll
        for (int j = 0; j < 4; ++j) acc[i][j] = (f32x4)0.0f;

    const int lk = (lane >> 4) * 8;
    const int lr = lane & 15;

#pragma unroll 1
    for (int k0 = 0; k0 < DD; k0 += Bb_K) {
        __syncthreads();                       // prev frag reads retired
        load_lds16(gA0 + k0, lA0);
        load_lds16(gA1 + k0, lA1);
        load_lds16(gB0 + k0, lB0);
        load_lds16(gB1 + k0, lB1);
        __syncthreads();                       // vmcnt(0) drain: DMA landed

        half8 af[4], bf[4];
#pragma unroll
        for (int tm = 0; tm < 4; ++tm)
            af[tm] = *(const half8*)&As[wm * 64 + tm * 16 + lr][lk];
#pragma unroll
        for (int tn = 0; tn < 4; ++tn)
            bf[tn] = *(const half8*)&Bs[wn * 64 + tn * 16 + lr][lk];
#pragma unroll
        for (int tm = 0; tm < 4; ++tm)
#pragma unroll
            for (int tn = 0; tn < 4; ++tn)
                acc[tm][tn] = __builtin_amdgcn_mfma_f32_16x16x32_f16(
                    af[tm], bf[tn], acc[tm][tn], 0, 0, 0);
    }

    // epilogue: partial energy per row over this wave's 64 cols
    float part[4][4];
#pragma unroll
    for (int tm = 0; tm < 4; ++tm) {
#pragma unroll
        for (int r = 0; r < 4; ++r) {
            float p = 0.f;
#pragma unroll
            for (int tn = 0; tn < 4; ++tn) {
                const int cl = wn * 64 + tn * 16 + lr;
                p += v_s[cl] * tanh_fast(acc[tm][tn][r] + ps_s[cl]);
            }
            part[tm][r] = p;
        }
    }
#pragma unroll
    for (int off = 1; off < 16; off <<= 1)
#pragma unroll
        for (int tm = 0; tm < 4; ++tm)
#pragma unroll
            for (int r = 0; r < 4; ++r)
                part[tm][r] += __shfl_xor(part[tm][r], off, 64);

    if ((lane & 15) == 0) {
        const int slot = nt * 2 + wn;          // 16 deterministic slots
#pragma unroll
        for (int tm = 0; tm < 4; ++tm)
#pragma unroll
            for (int r = 0; r < 4; ++r) {
                const int ci = ci0 + wm * 64 + tm * 16 + (lane >> 4) * 4 + r;
                epart[(long)slot * MM + b * TT + ci] = part[tm][r];
            }
    }
}

// ---------------------------------------------------------------------------
// softmax over the compacted (unmasked) set; masked t's get score 0.
__global__ void softmax_kernel(const float* __restrict__ epart,
                               const int* __restrict__ rowlist,
                               const int* __restrict__ cnts,
                               float* __restrict__ score) {
    const int b = blockIdx.x, tid = threadIdx.x;   // 32 x 256
    const int cnt = cnts[b];
    for (int t = tid; t < TT; t += 256) score[b * TT + t] = 0.0f;

    float e[8], mx = -1e30f;
#pragma unroll
    for (int i = 0; i < 8; ++i) {
        const int ci = i * 256 + tid;
        float sum = -1e30f;
        if (ci < cnt) {
            sum = 0.f;
#pragma unroll
            for (int p = 0; p < 16; ++p)
                sum += epart[(long)p * MM + b * TT + ci];
        }
        e[i] = sum;
        mx = fmaxf(mx, sum);
    }
#pragma unroll
    for (int off = 32; off > 0; off >>= 1) mx = fmaxf(mx, __shfl_xor(mx, off, 64));
    __shared__ float r4[4];
    if ((tid & 63) == 0) r4[tid >> 6] = mx;
    __syncthreads();
    mx = fmaxf(fmaxf(r4[0], r4[1]), fmaxf(r4[2], r4[3]));

    float tot = 0.f;
#pragma unroll
    for (int i = 0; i < 8; ++i) {
        const int ci = i * 256 + tid;
        e[i] = (ci < cnt) ? __expf(e[i] - mx) : 0.0f;
        tot += e[i];
    }
#pragma unroll
    for (int off = 32; off > 0; off >>= 1) tot += __shfl_xor(tot, off, 64);
    __shared__ float s4[4];
    if ((tid & 63) == 0) s4[tid >> 6] = tot;
    __syncthreads();                                // also orders the zero-fill
    tot = s4[0] + s4[1] + s4[2] + s4[3];
    const float inv = 1.0f / tot;
#pragma unroll
    for (int i = 0; i < 8; ++i) {
        const int ci = i * 256 + tid;
        if (ci < cnt)
            score[b * TT + rowlist[b * TT + ci]] = e[i] * inv;
    }
}

// ---------------------------------------------------------------------------
// context[b][d] = sum_t score·h16 ; score==0 (masked) rows skipped
__global__ void context_kernel(const _Float16* __restrict__ h16,
                               const float* __restrict__ score,
                               float* __restrict__ out) {
    const int tc = blockIdx.x;                 // 16 chunks x 128 t
    const int b  = blockIdx.y;
    const int d0 = threadIdx.x * 8;            // 128 thr x 8
    float a[8];
#pragma unroll
    for (int j = 0; j < 8; ++j) a[j] = 0.f;
    for (int i = 0; i < 128; ++i) {
        const int t = tc * 128 + i;
        const float sc = score[(long)b * TT + t];
        if (sc != 0.0f) {
            const half8 hv = *(const half8*)(h16 + ((long)(b * TT + t)) * DD + d0);
#pragma unroll
            for (int j = 0; j < 8; ++j) a[j] += sc * (float)hv[j];
        }
    }
#pragma unroll
    for (int j = 0; j < 8; ++j) atomicAdd(&out[b * DD + d0 + j], a[j]);
}

// ---------------------------------------------------------------------------
extern "C" void kernel_launch(void* const* d_in, const int* in_sizes, int n_in,
                              void* d_out, int out_size, void* d_ws, size_t ws_size,
                              hipStream_t stream) {
    const float* s    = (const float*)d_in[0];
    const float* h    = (const float*)d_in[1];
    const int*   mask = (const int*)  d_in[2];
    const float* W    = (const float*)d_in[3];
    const float* U    = (const float*)d_in[4];
    const float* v    = (const float*)d_in[5];
    float* out = (float*)d_out;

    // workspace layout (~135 MB; round-2 confirmed ws >= 140 MB)
    char* ws = (char*)d_ws;
    size_t off = 0;
    _Float16* h16 = (_Float16*)(ws + off); off += (size_t)MM * DD * 2;   // 128 MB
    _Float16* Ut  = (_Float16*)(ws + off); off += (size_t)HH * DD * 2;   // 2 MB
    float*    ps  = (float*)(ws + off);    off += (size_t)BB * HH * 4;   // 128 KB
    float*    ep  = (float*)(ws + off);    off += (size_t)16 * MM * 4;   // 4 MB
    float*    scr = (float*)(ws + off);    off += (size_t)MM * 4;        // 256 KB
    int*      rlist = (int*)(ws + off);    off += (size_t)MM * 4;        // 256 KB
    int*      cnts  = (int*)(ws + off);    off += 64 * 4;
    int*      tb    = (int*)(ws + off);    off += 512 * 4;
    int*      tci   = (int*)(ws + off);    off += 512 * 4;
    int*      ntl   = (int*)(ws + off);

    compact_kernel<<<BB, 256, 0, stream>>>(mask, rlist, cnts);
    tiles_kernel  <<<1, 64, 0, stream>>>(cnts, tb, tci, ntl);
    cast_h_kernel <<<MM / 2, 256, 0, stream>>>(h, mask, h16);
    prep_ut_kernel<<<dim3(32, 32), 256, 0, stream>>>(U, Ut);
    prep_ps_kernel<<<dim3(32, 4), 256, 0, stream>>>(s, W, ps, out);
    energy_gemm_kernel<<<dim3(8, 512), 256, 0, stream>>>(h16, Ut, ps, v,
                                                         rlist, tb, tci, ntl, ep);
    softmax_kernel<<<BB, 256, 0, stream>>>(ep, rlist, cnts, scr);
    context_kernel<<<dim3(16, 32), 128, 0, stream>>>(h16, scr, out);
}